// Round 9
// baseline (302.091 us; speedup 1.0000x reference)
//
#include <hip/hip_runtime.h>
#include <stdint.h>

typedef __bf16 bf16x8 __attribute__((ext_vector_type(8)));
typedef float  f32x4  __attribute__((ext_vector_type(4)));

#define DEV __device__ __forceinline__

constexpr int Bc = 4, S = 2048, D = 1024, Hh = 16, DH = 64;
constexpr int Kdim = 1024;   // inner K of both GEMMs

DEV unsigned short f2bf(float f) {
    uint32_t u = __builtin_bit_cast(uint32_t, f);
    u += 0x7fff + ((u >> 16) & 1);   // RNE
    return (unsigned short)(u >> 16);
}
DEV bf16x8 ld8(const unsigned short* p) {
    uint4 u = *(const uint4*)p;
    return __builtin_bit_cast(bf16x8, u);
}
DEV uint4 pack8(float4 a, float4 b) {
    union { uint4 u; unsigned short s[8]; } r;
    r.s[0] = f2bf(a.x); r.s[1] = f2bf(a.y); r.s[2] = f2bf(a.z); r.s[3] = f2bf(a.w);
    r.s[4] = f2bf(b.x); r.s[5] = f2bf(b.y); r.s[6] = f2bf(b.z); r.s[7] = f2bf(b.w);
    return r.u;
}

// async global->LDS, 16B per lane. LDS dest is wave-uniform base + lane*16 (HW).
DEV void gl16(const void* g, void* l) {
    __builtin_amdgcn_global_load_lds((__attribute__((address_space(1))) void*)g,
                                     (__attribute__((address_space(3))) void*)l,
                                     16, 0, 0);
}

// ---------- weight transpose + cvt (f32 [rows][cols] -> bf16 [cols][rows]) ------
__global__ __launch_bounds__(256) void transpose_cvt(const float* __restrict__ in,
                                                     unsigned short* __restrict__ out,
                                                     int rows, int cols) {
    __shared__ float t[32][33];
    int tx = threadIdx.x & 31, ty = threadIdx.x >> 5;  // 32 x 8
    int c = blockIdx.x * 32 + tx;
    int rbase = blockIdx.y * 32;
    for (int rr = 0; rr < 32; rr += 8)
        t[ty + rr][tx] = in[(size_t)(rbase + ty + rr) * cols + c];
    __syncthreads();
    int orbase = blockIdx.x * 32;
    for (int rr = 0; rr < 32; rr += 8)
        out[(size_t)(orbase + ty + rr) * rows + rbase + tx] = f2bf(t[tx][ty + rr]);
}

// ---------- x f32 -> bf16, once --------------------------------------------------
__global__ __launch_bounds__(256) void cvt_bf16(const float* __restrict__ in,
                                                unsigned short* __restrict__ out) {
    size_t i = (size_t)blockIdx.x * 256 + threadIdx.x;   // 8 elems per thread, exact grid
    const float4* p = (const float4*)(in + i * 8);
    float4 a = p[0], b = p[1];
    *(uint4*)(out + i * 8) = pack8(a, b);
}

// ---------- GEMM: C[M,N] = A_bf16[M,K] * Bt_bf16[N,K]^T + bias_f32 --------------
// Counted-vmcnt phase-convoy (T3+T4+T5): 128x256 tile, 8 waves (2M x 4N, each
// 64x64 out), BK=64, TRIPLE-buffered LDS (A 3x16KB + B 3x32KB = 144KB, 1 blk/CU).
// Tile t+2's 6 global_load_lds issue during tile t (4 in phase 0, 2 in phase 1);
// boundary wait = s_waitcnt vmcnt(6) -> NEVER drains to 0 in steady state; each
// staged tile gets a full tile-body (~1300cy) of latency cover. Two convoyed
// phases per K-tile (16 MFMA each, s_setprio around the cluster, barrier between)
// keep the 8 waves role-split so load-issue and MFMA overlap across waves.
// Rule-21 both-sides XOR swizzle (byte^=((row&7)<<4)) -> 0 bank conflicts (R3+).
// Grids: QKV (12,64)=768 blocks = 3 full rounds; proj (4,64)=256 = 1 round.
// mode 0: scatter bf16 into q/k [B,H,S,DH] and V TRANSPOSED [B,H,DH,S]
// mode 1: write f32 outf [M,N]
__global__ __launch_bounds__(512, 2) void gemm_bt(const unsigned short* __restrict__ A,
                                                  const unsigned short* __restrict__ Bt,
                                                  const float* __restrict__ bias,
                                                  int mode,
                                                  unsigned short* __restrict__ qo,
                                                  unsigned short* __restrict__ ko,
                                                  unsigned short* __restrict__ vo,
                                                  float* __restrict__ outf) {
    __shared__ __align__(16) unsigned short As[3][128 * 64];   // [m][k] swizzled, 128B rows
    __shared__ __align__(16) unsigned short Bs[3][256 * 64];   // [n][k] swizzled
    const int tid = threadIdx.x;
    const int wave = tid >> 6, lane = tid & 63, g = lane >> 4, ln = lane & 15;
    const int wm = wave >> 2, wn = wave & 3;          // 2x4 wave grid, 64x64 each
    // T1: bijective XCD swizzle (nwg = 768 or 256, both % 8 == 0)
    const int nwg = gridDim.x * gridDim.y;
    const int orig = blockIdx.y * gridDim.x + blockIdx.x;
    const int swz = (orig & 7) * (nwg >> 3) + (orig >> 3);
    const int m0 = (swz / gridDim.x) * 128, n0 = (swz % gridDim.x) * 256;

    f32x4 acc[4][4];                                  // [M_rep=4][N_rep=4]
    for (int i = 0; i < 4; i++)
        for (int j = 0; j < 4; j++) acc[i][j] = f32x4{0.f, 0.f, 0.f, 0.f};

    // A tile 128x64 = 16KB: 2 gl16/thread. B tile 256x64 = 32KB: 4 gl16/thread.
#define STAGE_A(buf, k0)                                                            \
    _Pragma("unroll")                                                               \
    for (int c = 0; c < 2; c++) {                                                   \
        int L = c * 8192 + tid * 16;                                                \
        int row = L >> 7;                                                           \
        int colb = (L & 127) ^ ((row & 7) << 4);                                    \
        gl16((const char*)A + ((size_t)(m0 + row) * Kdim + (k0)) * 2 + colb,        \
             (char*)As[buf] + c * 8192 + wave * 1024);                              \
    }
#define STAGE_B01(buf, k0)                                                          \
    _Pragma("unroll")                                                               \
    for (int c = 0; c < 2; c++) {                                                   \
        int L = c * 8192 + tid * 16;                                                \
        int row = L >> 7;                                                           \
        int colb = (L & 127) ^ ((row & 7) << 4);                                    \
        gl16((const char*)Bt + ((size_t)(n0 + row) * Kdim + (k0)) * 2 + colb,       \
             (char*)Bs[buf] + c * 8192 + wave * 1024);                              \
    }
#define STAGE_B23(buf, k0)                                                          \
    _Pragma("unroll")                                                               \
    for (int c = 2; c < 4; c++) {                                                   \
        int L = c * 8192 + tid * 16;                                                \
        int row = L >> 7;                                                           \
        int colb = (L & 127) ^ ((row & 7) << 4);                                    \
        gl16((const char*)Bt + ((size_t)(n0 + row) * Kdim + (k0)) * 2 + colb,       \
             (char*)Bs[buf] + c * 8192 + wave * 1024);                              \
    }

    // prologue: stage tiles 0 and 1; wait only tile 0 (vmcnt(6): tile 1 in flight)
    STAGE_A(0, 0);  STAGE_B01(0, 0);  STAGE_B23(0, 0);
    STAGE_A(1, 64); STAGE_B01(1, 64); STAGE_B23(1, 64);
    asm volatile("s_waitcnt vmcnt(6)" ::: "memory");
    __builtin_amdgcn_s_barrier();
    asm volatile("" ::: "memory");

#pragma unroll 1
    for (int t = 0; t < 16; t++) {
        const unsigned short* Asb = As[t % 3];
        const unsigned short* Bsb = Bs[t % 3];
        const int bufn = (t + 2) % 3;
        const int k2 = (t + 2) * 64;

        // ---- phase 0: issue 4 loads of tile t+2; B-frags (kept) + A-quad 0; 16 MFMA
        if (t + 2 < 16) { STAGE_A(bufn, k2); STAGE_B01(bufn, k2); }
        bf16x8 bfr[4][2];
#pragma unroll
        for (int v = 0; v < 4; v++)
#pragma unroll
            for (int kk = 0; kk < 2; kk++) {
                int rb = wn * 64 + v * 16 + ln;
                int co = kk * 64 + g * 16;
                bfr[v][kk] = ld8((const unsigned short*)((const char*)Bsb + rb * 128 + (co ^ ((rb & 7) << 4))));
            }
        {
            bf16x8 af[2][2];
#pragma unroll
            for (int u = 0; u < 2; u++)
#pragma unroll
                for (int kk = 0; kk < 2; kk++) {
                    int ra = wm * 64 + u * 16 + ln;
                    int co = kk * 64 + g * 16;
                    af[u][kk] = ld8((const unsigned short*)((const char*)Asb + ra * 128 + (co ^ ((ra & 7) << 4))));
                }
            __builtin_amdgcn_s_setprio(1);
#pragma unroll
            for (int kk = 0; kk < 2; kk++)
#pragma unroll
                for (int u = 0; u < 2; u++)
#pragma unroll
                    for (int v = 0; v < 4; v++)
                        acc[u][v] = __builtin_amdgcn_mfma_f32_16x16x32_bf16(af[u][kk], bfr[v][kk], acc[u][v], 0, 0, 0);
            __builtin_amdgcn_s_setprio(0);
        }
        __builtin_amdgcn_s_barrier();                  // phase convoy
        asm volatile("" ::: "memory");

        // ---- phase 1: issue last 2 loads of tile t+2; A-quad 1; 16 MFMA
        if (t + 2 < 16) { STAGE_B23(bufn, k2); }
        {
            bf16x8 af[2][2];
#pragma unroll
            for (int u = 0; u < 2; u++)
#pragma unroll
                for (int kk = 0; kk < 2; kk++) {
                    int ra = wm * 64 + 32 + u * 16 + ln;
                    int co = kk * 64 + g * 16;
                    af[u][kk] = ld8((const unsigned short*)((const char*)Asb + ra * 128 + (co ^ ((ra & 7) << 4))));
                }
            __builtin_amdgcn_s_setprio(1);
#pragma unroll
            for (int kk = 0; kk < 2; kk++)
#pragma unroll
                for (int u = 0; u < 2; u++)
#pragma unroll
                    for (int v = 0; v < 4; v++)
                        acc[2 + u][v] = __builtin_amdgcn_mfma_f32_16x16x32_bf16(af[u][kk], bfr[v][kk], acc[2 + u][v], 0, 0, 0);
            __builtin_amdgcn_s_setprio(0);
        }
        asm volatile("" ::: "memory");

        // ---- tile boundary: counted wait (t+1 landed; t+2 stays in flight)
        if (t + 1 < 16) {
            if (t + 2 < 16) asm volatile("s_waitcnt vmcnt(6)" ::: "memory");
            else            asm volatile("s_waitcnt vmcnt(0)" ::: "memory");
            __builtin_amdgcn_s_barrier();              // deposits visible to all waves
            asm volatile("" ::: "memory");
        }
    }
#undef STAGE_A
#undef STAGE_B01
#undef STAGE_B23

    // epilogue: C/D layout col=lane&15, row=(lane>>4)*4+reg (R1-proven scatter;
    // L2 write-back coalesces the V^T 2B scatter: measured WRITE ~= ideal)
    for (int mt = 0; mt < 4; mt++)
        for (int v = 0; v < 4; v++)
            for (int r = 0; r < 4; r++) {
                int m = m0 + wm * 64 + (mt >> 1) * 32 + (mt & 1) * 16 + g * 4 + r;
                int n = n0 + wn * 64 + v * 16 + ln;
                float val = acc[mt][v][r] + bias[n];
                if (mode == 0) {
                    int which = n >> 10, rem = n & 1023;
                    int hh = rem >> 6, dd = rem & 63;
                    int b = m >> 11, s = m & 2047;
                    int bh = (b << 4) + hh;
                    if (which == 0)      qo[((size_t)bh * S + s) * DH + dd] = f2bf(val);
                    else if (which == 1) ko[((size_t)bh * S + s) * DH + dd] = f2bf(val);
                    else                 vo[((size_t)bh * DH + dd) * S + s] = f2bf(val);  // V^T
                } else {
                    outf[(size_t)m * 1024 + n] = val;
                }
            }
}

// ---------- flash attention: R4-exact (best measured total: 264.5) --------------
// QBLK=128, 8 waves/block, single-buffered K/V staged via global_load_lds with
// rule-21 both-sides XOR swizzle; per-iter: stage -> __syncthreads -> QK ->
// softmax -> pack P -> rescale -> PV -> __syncthreads. 2 blocks/CU.
__global__ __launch_bounds__(512, 4) void attn_fwd(const unsigned short* __restrict__ qg,
                                                   const unsigned short* __restrict__ kg,
                                                   const unsigned short* __restrict__ vtg,
                                                   unsigned short* __restrict__ og) {
    __shared__ __align__(16) unsigned short Ks[128 * 64];  // [kv][dh] swizzled
    __shared__ __align__(16) unsigned short Vs[64 * 128];  // [dh][kv] swizzled
    __shared__ __align__(16) unsigned short P [128 * 136]; // probs [q][kv], wave-private rows
    const int idx = blockIdx.x;
    const int qt = 15 - (idx >> 6);                        // heavy tiles dispatch first
    const int bh = idx & 63;                               // idx%8 = bh%8 -> same-bh same XCD
    const int b = bh >> 4, h = bh & 15;
    const size_t base = (size_t)bh * S * DH;
    const unsigned short* qp = qg + base;
    const char* kpb  = (const char*)(kg  + base);
    const char* vtpb = (const char*)(vtg + base);          // [DH][S] bytes: row stride 4096
    const int tid = threadIdx.x, wave = tid >> 6, lane = tid & 63;
    const int g = lane >> 4, ln = lane & 15;
    const int q0 = qt * 128, wq = wave * 16;               // wave's q rows [q0+wq, +16)
    const int jn = qt + 1;

    // Q B-frag (B-layout: n=ln -> q=q0+wq+ln; k=c*32+g*8+j)
    bf16x8 qf[2];
    qf[0] = ld8(qp + (size_t)(q0 + wq + ln) * DH + g * 8);
    qf[1] = ld8(qp + (size_t)(q0 + wq + ln) * DH + 32 + g * 8);

    f32x4 o_t[4];
#pragma unroll
    for (int dt = 0; dt < 4; dt++) o_t[dt] = f32x4{0.f, 0.f, 0.f, 0.f};
    float m_ = -1e30f, l_ = 0.f;

#pragma unroll 1
    for (int j = 0; j < jn; j++) {
        // ---- stage tile j direct to LDS (16KB K + 16KB V; 512 thr * 16B * 2)
        const char* kj = kpb + (size_t)j * (128 * DH * 2);
        const char* vj = vtpb + j * 256;
#pragma unroll
        for (int c = 0; c < 2; c++) {
            int L = c * 8192 + tid * 16;
            int kr = L >> 7, kcb = L & 127;                // K: 128B rows
            gl16(kj + (size_t)kr * 128 + (kcb ^ ((kr & 7) << 4)),
                 (char*)Ks + c * 8192 + wave * 1024);
            int vr = L >> 8, vcb = L & 255;                // V^T: 256B rows in tile
            gl16(vj + (size_t)vr * 4096 + (vcb ^ ((vr & 15) << 4)),
                 (char*)Vs + c * 8192 + wave * 1024);
        }
        __syncthreads();   // drains vmcnt(0) then barrier: all waves' tiles visible

        // ---- S^T = K*Q^T : st[mt] C-layout kv=mt*16+g*4+r, q-col=ln
        f32x4 st[8];
#pragma unroll
        for (int mt = 0; mt < 8; mt++) {
            int row = mt * 16 + ln;
            int sw = (row & 7) << 4;
            const char* kb2 = (const char*)Ks + row * 128;
            bf16x8 kf0 = ld8((const unsigned short*)(kb2 + ((g * 16) ^ sw)));
            bf16x8 kf1 = ld8((const unsigned short*)(kb2 + ((64 + g * 16) ^ sw)));
            f32x4 t = f32x4{0.f, 0.f, 0.f, 0.f};
            t = __builtin_amdgcn_mfma_f32_16x16x32_bf16(kf0, qf[0], t, 0, 0, 0);
            t = __builtin_amdgcn_mfma_f32_16x16x32_bf16(kf1, qf[1], t, 0, 0, 0);
            st[mt] = t;
        }
        if (j == jn - 1) {   // diagonal: mask kv_global > q_global
            int qgl = q0 + wq + ln;
#pragma unroll
            for (int mt = 0; mt < 8; mt++)
#pragma unroll
                for (int r = 0; r < 4; r++) {
                    int kvg = j * 128 + mt * 16 + g * 4 + r;
                    if (kvg > qgl) st[mt][r] = -3e38f;
                }
        }
        // ---- online softmax: q = ln is lane-resident; kv spread over (g, mt, r)
        f32x4 mm = st[0];
#pragma unroll
        for (int mt = 1; mt < 8; mt++)
#pragma unroll
            for (int e = 0; e < 4; e++) mm[e] = fmaxf(mm[e], st[mt][e]);
        float mx = fmaxf(fmaxf(mm[0], mm[1]), fmaxf(mm[2], mm[3]));
        mx = fmaxf(mx, __shfl_xor(mx, 16));
        mx = fmaxf(mx, __shfl_xor(mx, 32));
        float mnew = fmaxf(m_, mx);
        float alpha = __expf((m_ - mnew) * 0.125f);
        f32x4 sv = f32x4{0.f, 0.f, 0.f, 0.f};
#pragma unroll
        for (int mt = 0; mt < 8; mt++) {
            f32x4 pr;
#pragma unroll
            for (int e = 0; e < 4; e++) pr[e] = __expf((st[mt][e] - mnew) * 0.125f);
            st[mt] = pr;
            sv += pr;
        }
        float rs = (sv[0] + sv[1]) + (sv[2] + sv[3]);
        rs += __shfl_xor(rs, 16);
        rs += __shfl_xor(rs, 32);
        l_ = l_ * alpha + rs;
        m_ = mnew;

        // ---- pack P (truncate f32->bf16) into [q][kv] rows (wave-private)
#pragma unroll
        for (int mt = 0; mt < 8; mt++) {
            uint4 u = __builtin_bit_cast(uint4, st[mt]);
            uint2 w;
            w.x = (u.y & 0xFFFF0000u) | (u.x >> 16);
            w.y = (u.w & 0xFFFF0000u) | (u.z >> 16);
            *(uint2*)&P[(wq + ln) * 136 + mt * 16 + g * 4] = w;
        }
        // ---- rescale O^T (cols = q = ln)
#pragma unroll
        for (int dt = 0; dt < 4; dt++) o_t[dt] *= alpha;

        // ---- PV: O^T += V^T * P^T (V from swizzled LDS, P from wave rows)
#pragma unroll
        for (int kc = 0; kc < 4; kc++) {
            bf16x8 pf = ld8(&P[(wq + ln) * 136 + kc * 32 + g * 8]);
            bf16x8 vf[4];
#pragma unroll
            for (int dt = 0; dt < 4; dt++) {
                int row = dt * 16 + ln;
                vf[dt] = ld8((const unsigned short*)((const char*)Vs + row * 256 +
                             ((kc * 64 + g * 16) ^ ((row & 15) << 4))));
            }
#pragma unroll
            for (int dt = 0; dt < 4; dt++)
                o_t[dt] = __builtin_amdgcn_mfma_f32_16x16x32_bf16(vf[dt], pf, o_t[dt], 0, 0, 0);
        }
        __syncthreads();   // all waves done reading Ks/Vs before next overwrite
    }

    // ---- epilogue: scale 1/l, transpose O^T via wave-private LDS, bf16 stores.
    //      Wave region = P rows [wq..wq+16) = [16][68] f32 (4352B, exact fit).
    float il = 1.f / l_;
#pragma unroll
    for (int dt = 0; dt < 4; dt++) o_t[dt] *= il;
    float* Ot = (float*)&P[wq * 136];
#pragma unroll
    for (int dt = 0; dt < 4; dt++)
        *(float4*)&Ot[ln * 68 + dt * 16 + g * 4] =
            float4{o_t[dt][0], o_t[dt][1], o_t[dt][2], o_t[dt][3]};
    // same-wave LDS RAW: DS ops are in-order per wave
#pragma unroll
    for (int i = 0; i < 4; i++) {
        float4 v = *(float4*)&Ot[(i * 4 + g) * 68 + ln * 4];
        uint2 w;
        w.x = (uint32_t)f2bf(v.x) | ((uint32_t)f2bf(v.y) << 16);
        w.y = (uint32_t)f2bf(v.z) | ((uint32_t)f2bf(v.w) << 16);
        *(uint2*)&og[((size_t)(b * S + q0 + wq + i * 4 + g)) * D + h * DH + ln * 4] = w;
    }
}

extern "C" void kernel_launch(void* const* d_in, const int* in_sizes, int n_in,
                              void* d_out, int out_size, void* d_ws, size_t ws_size,
                              hipStream_t stream) {
    (void)in_sizes; (void)n_in; (void)out_size; (void)ws_size;
    const float* x      = (const float*)d_in[0];  // [B,S,D] f32
    const float* w_attn = (const float*)d_in[1];  // [D,3D]  f32
    const float* b_attn = (const float*)d_in[2];  // [3D]    f32
    const float* w_proj = (const float*)d_in[3];  // [D,D]   f32
    const float* b_proj = (const float*)d_in[4];  // [D]     f32

    char* ws = (char*)d_ws;
    unsigned short* wattn_t = (unsigned short*)ws;                 // [3072][1024] bf16
    unsigned short* wproj_t = (unsigned short*)(ws + 6291456);     // [1024][1024] bf16
    unsigned short* xb      = (unsigned short*)(ws + 8388608);     // [B*S][D] bf16
    unsigned short* qb      = (unsigned short*)(ws + 25165824);    // [B,H,S,DH] bf16
    unsigned short* kb      = (unsigned short*)(ws + 41943040);
    unsigned short* vtb     = (unsigned short*)(ws + 58720256);    // [B,H,DH,S] bf16
    unsigned short* aob     = (unsigned short*)(ws + 75497472);    // [B,S,D] bf16

    transpose_cvt<<<dim3(96, 32), 256, 0, stream>>>(w_attn, wattn_t, 1024, 3072);
    transpose_cvt<<<dim3(32, 32), 256, 0, stream>>>(w_proj, wproj_t, 1024, 1024);
    cvt_bf16<<<dim3(4096), 256, 0, stream>>>(x, xb);
    gemm_bt<<<dim3(12, 64), 512, 0, stream>>>(xb, wattn_t, b_attn, 0, qb, kb, vtb, nullptr);
    attn_fwd<<<dim3(1024), 512, 0, stream>>>(qb, kb, vtb, aob);
    gemm_bt<<<dim3(4, 64), 512, 0, stream>>>(aob, wproj_t, b_proj, 1,
                                             nullptr, nullptr, nullptr, (float*)d_out);
}

// Round 10
// 267.925 us; speedup vs baseline: 1.1275x; 1.1275x over previous
//
#include <hip/hip_runtime.h>
#include <stdint.h>

typedef __bf16 bf16x8 __attribute__((ext_vector_type(8)));
typedef float  f32x4  __attribute__((ext_vector_type(4)));

#define DEV __device__ __forceinline__

constexpr int Bc = 4, S = 2048, D = 1024, Hh = 16, DH = 64;
constexpr int Kdim = 1024;   // inner K of both GEMMs

DEV unsigned short f2bf(float f) {
    uint32_t u = __builtin_bit_cast(uint32_t, f);
    u += 0x7fff + ((u >> 16) & 1);   // RNE
    return (unsigned short)(u >> 16);
}
DEV bf16x8 ld8(const unsigned short* p) {
    uint4 u = *(const uint4*)p;
    return __builtin_bit_cast(bf16x8, u);
}
DEV uint4 pack8(float4 a, float4 b) {
    union { uint4 u; unsigned short s[8]; } r;
    r.s[0] = f2bf(a.x); r.s[1] = f2bf(a.y); r.s[2] = f2bf(a.z); r.s[3] = f2bf(a.w);
    r.s[4] = f2bf(b.x); r.s[5] = f2bf(b.y); r.s[6] = f2bf(b.z); r.s[7] = f2bf(b.w);
    return r.u;
}

// async global->LDS, 16B per lane. LDS dest is wave-uniform base + lane*16 (HW).
DEV void gl16(const void* g, void* l) {
    __builtin_amdgcn_global_load_lds((__attribute__((address_space(1))) void*)g,
                                     (__attribute__((address_space(3))) void*)l,
                                     16, 0, 0);
}

// ---------- weight transpose + cvt (f32 [rows][cols] -> bf16 [cols][rows]) ------
__global__ __launch_bounds__(256) void transpose_cvt(const float* __restrict__ in,
                                                     unsigned short* __restrict__ out,
                                                     int rows, int cols) {
    __shared__ float t[32][33];
    int tx = threadIdx.x & 31, ty = threadIdx.x >> 5;  // 32 x 8
    int c = blockIdx.x * 32 + tx;
    int rbase = blockIdx.y * 32;
    for (int rr = 0; rr < 32; rr += 8)
        t[ty + rr][tx] = in[(size_t)(rbase + ty + rr) * cols + c];
    __syncthreads();
    int orbase = blockIdx.x * 32;
    for (int rr = 0; rr < 32; rr += 8)
        out[(size_t)(orbase + ty + rr) * rows + rbase + tx] = f2bf(t[tx][ty + rr]);
}

// ---------- x f32 -> bf16, once --------------------------------------------------
__global__ __launch_bounds__(256) void cvt_bf16(const float* __restrict__ in,
                                                unsigned short* __restrict__ out) {
    size_t i = (size_t)blockIdx.x * 256 + threadIdx.x;   // 8 elems per thread, exact grid
    const float4* p = (const float4*)(in + i * 8);
    float4 a = p[0], b = p[1];
    *(uint4*)(out + i * 8) = pack8(a, b);
}

// ---------- GEMM: C[M,N] = A_bf16[M,K] * Bt_bf16[N,K]^T + bias_f32 --------------
// R4-proven T3-minimum 2-phase (best measured: 94.6us QKV): double-buffered BK=64
// tiles via global_load_lds, STAGE(next) issued BEFORE computing current, vmcnt(0)
// hidden under 32 MFMA + 16 ds_read, ONE s_barrier per K-step. Rule-21 XOR
// swizzle -> 0 bank conflicts.
__global__ __launch_bounds__(256) void gemm_bt(const unsigned short* __restrict__ A,
                                               const unsigned short* __restrict__ Bt,
                                               const float* __restrict__ bias,
                                               int mode,
                                               unsigned short* __restrict__ qo,
                                               unsigned short* __restrict__ ko,
                                               unsigned short* __restrict__ vo,
                                               float* __restrict__ outf) {
    __shared__ __align__(16) unsigned short As[2][128 * 64];   // [m][k] swizzled, 128B rows
    __shared__ __align__(16) unsigned short Bs[2][128 * 64];   // [n][k] swizzled   (64KB total)
    const int tid = threadIdx.x;
    const int wave = tid >> 6, lane = tid & 63, g = lane >> 4, ln = lane & 15;
    const int wm = wave >> 1, wn = wave & 1;          // 2x2 wave grid, 64x64 each
    // T1: bijective XCD swizzle (nwg = 1536 or 512, both % 8 == 0)
    const int nwg = gridDim.x * gridDim.y;
    const int orig = blockIdx.y * gridDim.x + blockIdx.x;
    const int swz = (orig & 7) * (nwg >> 3) + (orig >> 3);
    const int m0 = (swz / gridDim.x) * 128, n0 = (swz % gridDim.x) * 128;

    f32x4 acc[4][4];
    for (int i = 0; i < 4; i++)
        for (int j = 0; j < 4; j++) acc[i][j] = f32x4{0.f, 0.f, 0.f, 0.f};

#define STAGE_G(buf, k0)                                                            \
    _Pragma("unroll")                                                               \
    for (int c = 0; c < 4; c++) {                                                   \
        int L = c * 4096 + tid * 16;                                                \
        int row = L >> 7;                                                           \
        int colb = (L & 127) ^ ((row & 7) << 4);                                    \
        gl16((const char*)A  + ((size_t)(m0 + row) * Kdim + (k0)) * 2 + colb,       \
             (char*)As[buf] + c * 4096 + wave * 1024);                              \
        gl16((const char*)Bt + ((size_t)(n0 + row) * Kdim + (k0)) * 2 + colb,       \
             (char*)Bs[buf] + c * 4096 + wave * 1024);                              \
    }

    STAGE_G(0, 0);
    asm volatile("s_waitcnt vmcnt(0)" ::: "memory");
    __builtin_amdgcn_s_barrier();
    asm volatile("" ::: "memory");

#pragma unroll 1
    for (int t = 0; t < 16; t++) {
        const int buf = t & 1;
        if (t + 1 < 16) STAGE_G(buf ^ 1, (t + 1) * 64);    // next tile in flight
        const unsigned short* Asb = As[buf];
        const unsigned short* Bsb = Bs[buf];
#pragma unroll
        for (int kk = 0; kk < 2; kk++) {
            bf16x8 af[4], bfr[4];
#pragma unroll
            for (int u = 0; u < 4; u++) {
                int ra = wm * 64 + u * 16 + ln;
                int rb = wn * 64 + u * 16 + ln;
                int co = kk * 64 + g * 16;
                af[u]  = ld8((const unsigned short*)((const char*)Asb + ra * 128 + (co ^ ((ra & 7) << 4))));
                bfr[u] = ld8((const unsigned short*)((const char*)Bsb + rb * 128 + (co ^ ((rb & 7) << 4))));
            }
#pragma unroll
            for (int mt = 0; mt < 4; mt++)
#pragma unroll
                for (int nt = 0; nt < 4; nt++)
                    acc[mt][nt] = __builtin_amdgcn_mfma_f32_16x16x32_bf16(af[mt], bfr[nt], acc[mt][nt], 0, 0, 0);
        }
        asm volatile("" ::: "memory");
        asm volatile("s_waitcnt vmcnt(0)" ::: "memory");   // next tile landed (flew under compute)
        __builtin_amdgcn_s_barrier();                      // reads done + deposits visible
        asm volatile("" ::: "memory");
    }
#undef STAGE_G

    // epilogue: C/D layout col=lane&15, row=(lane>>4)*4+reg (R1-proven scatter;
    // L2 write-back coalesces the V^T 2B scatter: measured WRITE ~= ideal)
    for (int mt = 0; mt < 4; mt++)
        for (int nt = 0; nt < 4; nt++)
            for (int r = 0; r < 4; r++) {
                int m = m0 + wm * 64 + mt * 16 + g * 4 + r;
                int n = n0 + wn * 64 + nt * 16 + ln;
                float val = acc[mt][nt][r] + bias[n];
                if (mode == 0) {
                    int which = n >> 10, rem = n & 1023;
                    int hh = rem >> 6, dd = rem & 63;
                    int b = m >> 11, s = m & 2047;
                    int bh = (b << 4) + hh;
                    if (which == 0)      qo[((size_t)bh * S + s) * DH + dd] = f2bf(val);
                    else if (which == 1) ko[((size_t)bh * S + s) * DH + dd] = f2bf(val);
                    else                 vo[((size_t)bh * DH + dd) * S + s] = f2bf(val);  // V^T
                } else {
                    outf[(size_t)m * 1024 + n] = val;
                }
            }
}

// ---------- flash attention: R4 inner structure + static pair-balancing ---------
// QBLK=128, 8 waves/block, single-buffered K/V staged via global_load_lds with
// rule-21 both-sides XOR swizzle; per-iter: stage -> __syncthreads -> QK ->
// softmax -> pack P -> rescale -> PV -> __syncthreads. 2 blocks/CU.
// NEW: grid 512 = 64 bh x 8 pairs; each block runs q-tile (15-pair) then (pair):
// jn sums to 17 for EVERY block -> all 512 blocks co-resident in one round,
// perfectly balanced makespan (ideal 8704/512 = 17 iter-slots), zero tail.
__global__ __launch_bounds__(512, 4) void attn_fwd(const unsigned short* __restrict__ qg,
                                                   const unsigned short* __restrict__ kg,
                                                   const unsigned short* __restrict__ vtg,
                                                   unsigned short* __restrict__ og) {
    __shared__ __align__(16) unsigned short Ks[128 * 64];  // [kv][dh] swizzled
    __shared__ __align__(16) unsigned short Vs[64 * 128];  // [dh][kv] swizzled
    __shared__ __align__(16) unsigned short P [128 * 136]; // probs [q][kv], wave-private rows
    const int idx = blockIdx.x;
    const int pair = idx >> 6;                             // 0..7
    const int bh = idx & 63;                               // idx%8 = bh%8 -> same-bh same XCD
    const int b = bh >> 4, h = bh & 15;
    const size_t base = (size_t)bh * S * DH;
    const unsigned short* qp = qg + base;
    const char* kpb  = (const char*)(kg  + base);
    const char* vtpb = (const char*)(vtg + base);          // [DH][S] bytes: row stride 4096
    const int tid = threadIdx.x, wave = tid >> 6, lane = tid & 63;
    const int g = lane >> 4, ln = lane & 15;
    const int wq = wave * 16;                              // wave's q rows [q0+wq, +16)

#pragma unroll 1
    for (int t2 = 0; t2 < 2; t2++) {
        const int qt = t2 ? pair : (15 - pair);            // heavy tile first
        const int q0 = qt * 128;
        const int jn = qt + 1;

        // Q B-frag (B-layout: n=ln -> q=q0+wq+ln; k=c*32+g*8+j)
        bf16x8 qf[2];
        qf[0] = ld8(qp + (size_t)(q0 + wq + ln) * DH + g * 8);
        qf[1] = ld8(qp + (size_t)(q0 + wq + ln) * DH + 32 + g * 8);

        f32x4 o_t[4];
#pragma unroll
        for (int dt = 0; dt < 4; dt++) o_t[dt] = f32x4{0.f, 0.f, 0.f, 0.f};
        float m_ = -1e30f, l_ = 0.f;

#pragma unroll 1
        for (int j = 0; j < jn; j++) {
            // ---- stage tile j direct to LDS (16KB K + 16KB V; 512 thr * 16B * 2)
            const char* kj = kpb + (size_t)j * (128 * DH * 2);
            const char* vj = vtpb + j * 256;
#pragma unroll
            for (int c = 0; c < 2; c++) {
                int L = c * 8192 + tid * 16;
                int kr = L >> 7, kcb = L & 127;            // K: 128B rows
                gl16(kj + (size_t)kr * 128 + (kcb ^ ((kr & 7) << 4)),
                     (char*)Ks + c * 8192 + wave * 1024);
                int vr = L >> 8, vcb = L & 255;            // V^T: 256B rows in tile
                gl16(vj + (size_t)vr * 4096 + (vcb ^ ((vr & 15) << 4)),
                     (char*)Vs + c * 8192 + wave * 1024);
            }
            __syncthreads();   // drains vmcnt(0) then barrier: all waves' tiles visible

            // ---- S^T = K*Q^T : st[mt] C-layout kv=mt*16+g*4+r, q-col=ln
            f32x4 st[8];
#pragma unroll
            for (int mt = 0; mt < 8; mt++) {
                int row = mt * 16 + ln;
                int sw = (row & 7) << 4;
                const char* kb2 = (const char*)Ks + row * 128;
                bf16x8 kf0 = ld8((const unsigned short*)(kb2 + ((g * 16) ^ sw)));
                bf16x8 kf1 = ld8((const unsigned short*)(kb2 + ((64 + g * 16) ^ sw)));
                f32x4 t = f32x4{0.f, 0.f, 0.f, 0.f};
                t = __builtin_amdgcn_mfma_f32_16x16x32_bf16(kf0, qf[0], t, 0, 0, 0);
                t = __builtin_amdgcn_mfma_f32_16x16x32_bf16(kf1, qf[1], t, 0, 0, 0);
                st[mt] = t;
            }
            if (j == jn - 1) {   // diagonal: mask kv_global > q_global
                int qgl = q0 + wq + ln;
#pragma unroll
                for (int mt = 0; mt < 8; mt++)
#pragma unroll
                    for (int r = 0; r < 4; r++) {
                        int kvg = j * 128 + mt * 16 + g * 4 + r;
                        if (kvg > qgl) st[mt][r] = -3e38f;
                    }
            }
            // ---- online softmax: q = ln is lane-resident; kv spread over (g, mt, r)
            f32x4 mm = st[0];
#pragma unroll
            for (int mt = 1; mt < 8; mt++)
#pragma unroll
                for (int e = 0; e < 4; e++) mm[e] = fmaxf(mm[e], st[mt][e]);
            float mx = fmaxf(fmaxf(mm[0], mm[1]), fmaxf(mm[2], mm[3]));
            mx = fmaxf(mx, __shfl_xor(mx, 16));
            mx = fmaxf(mx, __shfl_xor(mx, 32));
            float mnew = fmaxf(m_, mx);
            float alpha = __expf((m_ - mnew) * 0.125f);
            f32x4 sv = f32x4{0.f, 0.f, 0.f, 0.f};
#pragma unroll
            for (int mt = 0; mt < 8; mt++) {
                f32x4 pr;
#pragma unroll
                for (int e = 0; e < 4; e++) pr[e] = __expf((st[mt][e] - mnew) * 0.125f);
                st[mt] = pr;
                sv += pr;
            }
            float rs = (sv[0] + sv[1]) + (sv[2] + sv[3]);
            rs += __shfl_xor(rs, 16);
            rs += __shfl_xor(rs, 32);
            l_ = l_ * alpha + rs;
            m_ = mnew;

            // ---- pack P (truncate f32->bf16) into [q][kv] rows (wave-private)
#pragma unroll
            for (int mt = 0; mt < 8; mt++) {
                uint4 u = __builtin_bit_cast(uint4, st[mt]);
                uint2 w;
                w.x = (u.y & 0xFFFF0000u) | (u.x >> 16);
                w.y = (u.w & 0xFFFF0000u) | (u.z >> 16);
                *(uint2*)&P[(wq + ln) * 136 + mt * 16 + g * 4] = w;
            }
            // ---- rescale O^T (cols = q = ln)
#pragma unroll
            for (int dt = 0; dt < 4; dt++) o_t[dt] *= alpha;

            // ---- PV: O^T += V^T * P^T (V from swizzled LDS, P from wave rows)
#pragma unroll
            for (int kc = 0; kc < 4; kc++) {
                bf16x8 pf = ld8(&P[(wq + ln) * 136 + kc * 32 + g * 8]);
                bf16x8 vf[4];
#pragma unroll
                for (int dt = 0; dt < 4; dt++) {
                    int row = dt * 16 + ln;
                    vf[dt] = ld8((const unsigned short*)((const char*)Vs + row * 256 +
                                 ((kc * 64 + g * 16) ^ ((row & 15) << 4))));
                }
#pragma unroll
                for (int dt = 0; dt < 4; dt++)
                    o_t[dt] = __builtin_amdgcn_mfma_f32_16x16x32_bf16(vf[dt], pf, o_t[dt], 0, 0, 0);
            }
            __syncthreads();   // all waves done reading Ks/Vs before next overwrite
        }

        // ---- epilogue: scale 1/l, transpose O^T via wave-private LDS, bf16 stores.
        //      Wave region = P rows [wq..wq+16) = [16][68] f32 (4352B, exact fit).
        float il = 1.f / l_;
#pragma unroll
        for (int dt = 0; dt < 4; dt++) o_t[dt] *= il;
        float* Ot = (float*)&P[wq * 136];
#pragma unroll
        for (int dt = 0; dt < 4; dt++)
            *(float4*)&Ot[ln * 68 + dt * 16 + g * 4] =
                float4{o_t[dt][0], o_t[dt][1], o_t[dt][2], o_t[dt][3]};
        // same-wave LDS RAW: DS ops are in-order per wave
#pragma unroll
        for (int i = 0; i < 4; i++) {
            float4 v = *(float4*)&Ot[(i * 4 + g) * 68 + ln * 4];
            uint2 w;
            w.x = (uint32_t)f2bf(v.x) | ((uint32_t)f2bf(v.y) << 16);
            w.y = (uint32_t)f2bf(v.z) | ((uint32_t)f2bf(v.w) << 16);
            *(uint2*)&og[((size_t)(b * S + q0 + wq + i * 4 + g)) * D + h * DH + ln * 4] = w;
        }
    }
}

extern "C" void kernel_launch(void* const* d_in, const int* in_sizes, int n_in,
                              void* d_out, int out_size, void* d_ws, size_t ws_size,
                              hipStream_t stream) {
    (void)in_sizes; (void)n_in; (void)out_size; (void)ws_size;
    const float* x      = (const float*)d_in[0];  // [B,S,D] f32
    const float* w_attn = (const float*)d_in[1];  // [D,3D]  f32
    const float* b_attn = (const float*)d_in[2];  // [3D]    f32
    const float* w_proj = (const float*)d_in[3];  // [D,D]   f32
    const float* b_proj = (const float*)d_in[4];  // [D]     f32

    char* ws = (char*)d_ws;
    unsigned short* wattn_t = (unsigned short*)ws;                 // [3072][1024] bf16
    unsigned short* wproj_t = (unsigned short*)(ws + 6291456);     // [1024][1024] bf16
    unsigned short* xb      = (unsigned short*)(ws + 8388608);     // [B*S][D] bf16
    unsigned short* qb      = (unsigned short*)(ws + 25165824);    // [B,H,S,DH] bf16
    unsigned short* kb      = (unsigned short*)(ws + 41943040);
    unsigned short* vtb     = (unsigned short*)(ws + 58720256);    // [B,H,DH,S] bf16
    unsigned short* aob     = (unsigned short*)(ws + 75497472);    // [B,S,D] bf16

    transpose_cvt<<<dim3(96, 32), 256, 0, stream>>>(w_attn, wattn_t, 1024, 3072);
    transpose_cvt<<<dim3(32, 32), 256, 0, stream>>>(w_proj, wproj_t, 1024, 1024);
    cvt_bf16<<<dim3(4096), 256, 0, stream>>>(x, xb);
    gemm_bt<<<dim3(24, 64), 256, 0, stream>>>(xb, wattn_t, b_attn, 0, qb, kb, vtb, nullptr);
    attn_fwd<<<dim3(512), 512, 0, stream>>>(qb, kb, vtb, aob);
    gemm_bt<<<dim3(8, 64), 256, 0, stream>>>(aob, wproj_t, b_proj, 1,
                                             nullptr, nullptr, nullptr, (float*)d_out);
}

// Round 11
// 261.801 us; speedup vs baseline: 1.1539x; 1.0234x over previous
//
#include <hip/hip_runtime.h>
#include <stdint.h>

typedef __bf16 bf16x8 __attribute__((ext_vector_type(8)));
typedef float  f32x4  __attribute__((ext_vector_type(4)));

#define DEV __device__ __forceinline__

constexpr int Bc = 4, S = 2048, D = 1024, Hh = 16, DH = 64;
constexpr int Kdim = 1024;   // inner K of both GEMMs

DEV unsigned short f2bf(float f) {
    uint32_t u = __builtin_bit_cast(uint32_t, f);
    u += 0x7fff + ((u >> 16) & 1);   // RNE
    return (unsigned short)(u >> 16);
}
DEV bf16x8 ld8(const unsigned short* p) {
    uint4 u = *(const uint4*)p;
    return __builtin_bit_cast(bf16x8, u);
}
DEV uint4 pack8(float4 a, float4 b) {
    union { uint4 u; unsigned short s[8]; } r;
    r.s[0] = f2bf(a.x); r.s[1] = f2bf(a.y); r.s[2] = f2bf(a.z); r.s[3] = f2bf(a.w);
    r.s[4] = f2bf(b.x); r.s[5] = f2bf(b.y); r.s[6] = f2bf(b.z); r.s[7] = f2bf(b.w);
    return r.u;
}

// async global->LDS, 16B per lane. LDS dest is wave-uniform base + lane*16 (HW).
DEV void gl16(const void* g, void* l) {
    __builtin_amdgcn_global_load_lds((__attribute__((address_space(1))) void*)g,
                                     (__attribute__((address_space(3))) void*)l,
                                     16, 0, 0);
}

// ---------- fused prep: x f32->bf16 + both weight transposes, ONE dispatch ------
// blocks [0,4096): cvt 8 elems/thread; [4096,7168): w_attn 32x32 transpose tiles;
// [7168,8192): w_proj tiles. Whole blocks take one branch -> no divergence.
__global__ __launch_bounds__(256) void prep_fused(const float* __restrict__ x,
                                                  const float* __restrict__ w_attn,
                                                  const float* __restrict__ w_proj,
                                                  unsigned short* __restrict__ xb,
                                                  unsigned short* __restrict__ wattn_t,
                                                  unsigned short* __restrict__ wproj_t) {
    __shared__ float t[32][33];
    const int bid = blockIdx.x;
    if (bid < 4096) {
        size_t i = (size_t)bid * 256 + threadIdx.x;      // 8 elems per thread, exact
        const float4* p = (const float4*)(x + i * 8);
        float4 a = p[0], b = p[1];
        *(uint4*)(xb + i * 8) = pack8(a, b);
        return;
    }
    const float* in;
    unsigned short* out;
    int bx, by, rows, cols;
    if (bid < 4096 + 3072) {
        int b2 = bid - 4096;
        in = w_attn; out = wattn_t; rows = 1024; cols = 3072;
        bx = b2 % 96; by = b2 / 96;
    } else {
        int b2 = bid - 7168;
        in = w_proj; out = wproj_t; rows = 1024; cols = 1024;
        bx = b2 & 31; by = b2 >> 5;
    }
    int tx = threadIdx.x & 31, ty = threadIdx.x >> 5;    // 32 x 8
    int c = bx * 32 + tx;
    int rbase = by * 32;
    for (int rr = 0; rr < 32; rr += 8)
        t[ty + rr][tx] = in[(size_t)(rbase + ty + rr) * cols + c];
    __syncthreads();
    int orbase = bx * 32;
    for (int rr = 0; rr < 32; rr += 8)
        out[(size_t)(orbase + ty + rr) * rows + rbase + tx] = f2bf(t[tx][ty + rr]);
}

// ---------- GEMM: C[M,N] = A_bf16[M,K] * Bt_bf16[N,K]^T + bias_f32 --------------
// R4-proven T3-minimum 2-phase (best measured: 94.6us QKV): double-buffered BK=64
// tiles via global_load_lds, STAGE(next) issued BEFORE computing current, vmcnt(0)
// hidden under 32 MFMA + 16 ds_read, ONE s_barrier per K-step. Rule-21 XOR
// swizzle -> 0 bank conflicts.
__global__ __launch_bounds__(256) void gemm_bt(const unsigned short* __restrict__ A,
                                               const unsigned short* __restrict__ Bt,
                                               const float* __restrict__ bias,
                                               int mode,
                                               unsigned short* __restrict__ qo,
                                               unsigned short* __restrict__ ko,
                                               unsigned short* __restrict__ vo,
                                               float* __restrict__ outf) {
    __shared__ __align__(16) unsigned short As[2][128 * 64];   // [m][k] swizzled, 128B rows
    __shared__ __align__(16) unsigned short Bs[2][128 * 64];   // [n][k] swizzled   (64KB total)
    const int tid = threadIdx.x;
    const int wave = tid >> 6, lane = tid & 63, g = lane >> 4, ln = lane & 15;
    const int wm = wave >> 1, wn = wave & 1;          // 2x2 wave grid, 64x64 each
    // T1: bijective XCD swizzle (nwg = 1536 or 512, both % 8 == 0)
    const int nwg = gridDim.x * gridDim.y;
    const int orig = blockIdx.y * gridDim.x + blockIdx.x;
    const int swz = (orig & 7) * (nwg >> 3) + (orig >> 3);
    const int m0 = (swz / gridDim.x) * 128, n0 = (swz % gridDim.x) * 128;

    f32x4 acc[4][4];
    for (int i = 0; i < 4; i++)
        for (int j = 0; j < 4; j++) acc[i][j] = f32x4{0.f, 0.f, 0.f, 0.f};

#define STAGE_G(buf, k0)                                                            \
    _Pragma("unroll")                                                               \
    for (int c = 0; c < 4; c++) {                                                   \
        int L = c * 4096 + tid * 16;                                                \
        int row = L >> 7;                                                           \
        int colb = (L & 127) ^ ((row & 7) << 4);                                    \
        gl16((const char*)A  + ((size_t)(m0 + row) * Kdim + (k0)) * 2 + colb,       \
             (char*)As[buf] + c * 4096 + wave * 1024);                              \
        gl16((const char*)Bt + ((size_t)(n0 + row) * Kdim + (k0)) * 2 + colb,       \
             (char*)Bs[buf] + c * 4096 + wave * 1024);                              \
    }

    STAGE_G(0, 0);
    asm volatile("s_waitcnt vmcnt(0)" ::: "memory");
    __builtin_amdgcn_s_barrier();
    asm volatile("" ::: "memory");

#pragma unroll 1
    for (int t = 0; t < 16; t++) {
        const int buf = t & 1;
        if (t + 1 < 16) STAGE_G(buf ^ 1, (t + 1) * 64);    // next tile in flight
        const unsigned short* Asb = As[buf];
        const unsigned short* Bsb = Bs[buf];
#pragma unroll
        for (int kk = 0; kk < 2; kk++) {
            bf16x8 af[4], bfr[4];
#pragma unroll
            for (int u = 0; u < 4; u++) {
                int ra = wm * 64 + u * 16 + ln;
                int rb = wn * 64 + u * 16 + ln;
                int co = kk * 64 + g * 16;
                af[u]  = ld8((const unsigned short*)((const char*)Asb + ra * 128 + (co ^ ((ra & 7) << 4))));
                bfr[u] = ld8((const unsigned short*)((const char*)Bsb + rb * 128 + (co ^ ((rb & 7) << 4))));
            }
#pragma unroll
            for (int mt = 0; mt < 4; mt++)
#pragma unroll
                for (int nt = 0; nt < 4; nt++)
                    acc[mt][nt] = __builtin_amdgcn_mfma_f32_16x16x32_bf16(af[mt], bfr[nt], acc[mt][nt], 0, 0, 0);
        }
        asm volatile("" ::: "memory");
        asm volatile("s_waitcnt vmcnt(0)" ::: "memory");   // next tile landed (flew under compute)
        __builtin_amdgcn_s_barrier();                      // reads done + deposits visible
        asm volatile("" ::: "memory");
    }
#undef STAGE_G

    // epilogue: C/D layout col=lane&15, row=(lane>>4)*4+reg (R1-proven scatter;
    // L2 write-back coalesces the V^T 2B scatter: measured WRITE ~= ideal)
    for (int mt = 0; mt < 4; mt++)
        for (int nt = 0; nt < 4; nt++)
            for (int r = 0; r < 4; r++) {
                int m = m0 + wm * 64 + mt * 16 + g * 4 + r;
                int n = n0 + wn * 64 + nt * 16 + ln;
                float val = acc[mt][nt][r] + bias[n];
                if (mode == 0) {
                    int which = n >> 10, rem = n & 1023;
                    int hh = rem >> 6, dd = rem & 63;
                    int b = m >> 11, s = m & 2047;
                    int bh = (b << 4) + hh;
                    if (which == 0)      qo[((size_t)bh * S + s) * DH + dd] = f2bf(val);
                    else if (which == 1) ko[((size_t)bh * S + s) * DH + dd] = f2bf(val);
                    else                 vo[((size_t)bh * DH + dd) * S + s] = f2bf(val);  // V^T
                } else {
                    outf[(size_t)m * 1024 + n] = val;
                }
            }
}

// ---------- flash attention: R4 inner structure + static pair-balancing ---------
// QBLK=128, 8 waves/block, single-buffered K/V staged via global_load_lds with
// rule-21 both-sides XOR swizzle; per-iter: stage -> __syncthreads -> QK ->
// softmax -> pack P -> rescale -> PV -> __syncthreads. 2 blocks/CU.
// grid 512 = 64 bh x 8 pairs; each block runs q-tile (15-pair) then (pair):
// jn sums to 17 for EVERY block -> all 512 blocks co-resident in one round,
// perfectly balanced makespan (ideal 8704/512 = 17 iter-slots), zero tail.
__global__ __launch_bounds__(512, 4) void attn_fwd(const unsigned short* __restrict__ qg,
                                                   const unsigned short* __restrict__ kg,
                                                   const unsigned short* __restrict__ vtg,
                                                   unsigned short* __restrict__ og) {
    __shared__ __align__(16) unsigned short Ks[128 * 64];  // [kv][dh] swizzled
    __shared__ __align__(16) unsigned short Vs[64 * 128];  // [dh][kv] swizzled
    __shared__ __align__(16) unsigned short P [128 * 136]; // probs [q][kv], wave-private rows
    const int idx = blockIdx.x;
    const int pair = idx >> 6;                             // 0..7
    const int bh = idx & 63;                               // idx%8 = bh%8 -> same-bh same XCD
    const int b = bh >> 4, h = bh & 15;
    const size_t base = (size_t)bh * S * DH;
    const unsigned short* qp = qg + base;
    const char* kpb  = (const char*)(kg  + base);
    const char* vtpb = (const char*)(vtg + base);          // [DH][S] bytes: row stride 4096
    const int tid = threadIdx.x, wave = tid >> 6, lane = tid & 63;
    const int g = lane >> 4, ln = lane & 15;
    const int wq = wave * 16;                              // wave's q rows [q0+wq, +16)

#pragma unroll 1
    for (int t2 = 0; t2 < 2; t2++) {
        const int qt = t2 ? pair : (15 - pair);            // heavy tile first
        const int q0 = qt * 128;
        const int jn = qt + 1;

        // Q B-frag (B-layout: n=ln -> q=q0+wq+ln; k=c*32+g*8+j)
        bf16x8 qf[2];
        qf[0] = ld8(qp + (size_t)(q0 + wq + ln) * DH + g * 8);
        qf[1] = ld8(qp + (size_t)(q0 + wq + ln) * DH + 32 + g * 8);

        f32x4 o_t[4];
#pragma unroll
        for (int dt = 0; dt < 4; dt++) o_t[dt] = f32x4{0.f, 0.f, 0.f, 0.f};
        float m_ = -1e30f, l_ = 0.f;

#pragma unroll 1
        for (int j = 0; j < jn; j++) {
            // ---- stage tile j direct to LDS (16KB K + 16KB V; 512 thr * 16B * 2)
            const char* kj = kpb + (size_t)j * (128 * DH * 2);
            const char* vj = vtpb + j * 256;
#pragma unroll
            for (int c = 0; c < 2; c++) {
                int L = c * 8192 + tid * 16;
                int kr = L >> 7, kcb = L & 127;            // K: 128B rows
                gl16(kj + (size_t)kr * 128 + (kcb ^ ((kr & 7) << 4)),
                     (char*)Ks + c * 8192 + wave * 1024);
                int vr = L >> 8, vcb = L & 255;            // V^T: 256B rows in tile
                gl16(vj + (size_t)vr * 4096 + (vcb ^ ((vr & 15) << 4)),
                     (char*)Vs + c * 8192 + wave * 1024);
            }
            __syncthreads();   // drains vmcnt(0) then barrier: all waves' tiles visible

            // ---- S^T = K*Q^T : st[mt] C-layout kv=mt*16+g*4+r, q-col=ln
            f32x4 st[8];
#pragma unroll
            for (int mt = 0; mt < 8; mt++) {
                int row = mt * 16 + ln;
                int sw = (row & 7) << 4;
                const char* kb2 = (const char*)Ks + row * 128;
                bf16x8 kf0 = ld8((const unsigned short*)(kb2 + ((g * 16) ^ sw)));
                bf16x8 kf1 = ld8((const unsigned short*)(kb2 + ((64 + g * 16) ^ sw)));
                f32x4 t = f32x4{0.f, 0.f, 0.f, 0.f};
                t = __builtin_amdgcn_mfma_f32_16x16x32_bf16(kf0, qf[0], t, 0, 0, 0);
                t = __builtin_amdgcn_mfma_f32_16x16x32_bf16(kf1, qf[1], t, 0, 0, 0);
                st[mt] = t;
            }
            if (j == jn - 1) {   // diagonal: mask kv_global > q_global
                int qgl = q0 + wq + ln;
#pragma unroll
                for (int mt = 0; mt < 8; mt++)
#pragma unroll
                    for (int r = 0; r < 4; r++) {
                        int kvg = j * 128 + mt * 16 + g * 4 + r;
                        if (kvg > qgl) st[mt][r] = -3e38f;
                    }
            }
            // ---- online softmax: q = ln is lane-resident; kv spread over (g, mt, r)
            f32x4 mm = st[0];
#pragma unroll
            for (int mt = 1; mt < 8; mt++)
#pragma unroll
                for (int e = 0; e < 4; e++) mm[e] = fmaxf(mm[e], st[mt][e]);
            float mx = fmaxf(fmaxf(mm[0], mm[1]), fmaxf(mm[2], mm[3]));
            mx = fmaxf(mx, __shfl_xor(mx, 16));
            mx = fmaxf(mx, __shfl_xor(mx, 32));
            float mnew = fmaxf(m_, mx);
            float alpha = __expf((m_ - mnew) * 0.125f);
            f32x4 sv = f32x4{0.f, 0.f, 0.f, 0.f};
#pragma unroll
            for (int mt = 0; mt < 8; mt++) {
                f32x4 pr;
#pragma unroll
                for (int e = 0; e < 4; e++) pr[e] = __expf((st[mt][e] - mnew) * 0.125f);
                st[mt] = pr;
                sv += pr;
            }
            float rs = (sv[0] + sv[1]) + (sv[2] + sv[3]);
            rs += __shfl_xor(rs, 16);
            rs += __shfl_xor(rs, 32);
            l_ = l_ * alpha + rs;
            m_ = mnew;

            // ---- pack P (truncate f32->bf16) into [q][kv] rows (wave-private)
#pragma unroll
            for (int mt = 0; mt < 8; mt++) {
                uint4 u = __builtin_bit_cast(uint4, st[mt]);
                uint2 w;
                w.x = (u.y & 0xFFFF0000u) | (u.x >> 16);
                w.y = (u.w & 0xFFFF0000u) | (u.z >> 16);
                *(uint2*)&P[(wq + ln) * 136 + mt * 16 + g * 4] = w;
            }
            // ---- rescale O^T (cols = q = ln)
#pragma unroll
            for (int dt = 0; dt < 4; dt++) o_t[dt] *= alpha;

            // ---- PV: O^T += V^T * P^T (V from swizzled LDS, P from wave rows)
#pragma unroll
            for (int kc = 0; kc < 4; kc++) {
                bf16x8 pf = ld8(&P[(wq + ln) * 136 + kc * 32 + g * 8]);
                bf16x8 vf[4];
#pragma unroll
                for (int dt = 0; dt < 4; dt++) {
                    int row = dt * 16 + ln;
                    vf[dt] = ld8((const unsigned short*)((const char*)Vs + row * 256 +
                                 ((kc * 64 + g * 16) ^ ((row & 15) << 4))));
                }
#pragma unroll
                for (int dt = 0; dt < 4; dt++)
                    o_t[dt] = __builtin_amdgcn_mfma_f32_16x16x32_bf16(vf[dt], pf, o_t[dt], 0, 0, 0);
            }
            __syncthreads();   // all waves done reading Ks/Vs before next overwrite
        }

        // ---- epilogue: scale 1/l, transpose O^T via wave-private LDS, bf16 stores.
        //      Wave region = P rows [wq..wq+16) = [16][68] f32 (4352B, exact fit).
        float il = 1.f / l_;
#pragma unroll
        for (int dt = 0; dt < 4; dt++) o_t[dt] *= il;
        float* Ot = (float*)&P[wq * 136];
#pragma unroll
        for (int dt = 0; dt < 4; dt++)
            *(float4*)&Ot[ln * 68 + dt * 16 + g * 4] =
                float4{o_t[dt][0], o_t[dt][1], o_t[dt][2], o_t[dt][3]};
        // same-wave LDS RAW: DS ops are in-order per wave
#pragma unroll
        for (int i = 0; i < 4; i++) {
            float4 v = *(float4*)&Ot[(i * 4 + g) * 68 + ln * 4];
            uint2 w;
            w.x = (uint32_t)f2bf(v.x) | ((uint32_t)f2bf(v.y) << 16);
            w.y = (uint32_t)f2bf(v.z) | ((uint32_t)f2bf(v.w) << 16);
            *(uint2*)&og[((size_t)(b * S + q0 + wq + i * 4 + g)) * D + h * DH + ln * 4] = w;
        }
    }
}

extern "C" void kernel_launch(void* const* d_in, const int* in_sizes, int n_in,
                              void* d_out, int out_size, void* d_ws, size_t ws_size,
                              hipStream_t stream) {
    (void)in_sizes; (void)n_in; (void)out_size; (void)ws_size;
    const float* x      = (const float*)d_in[0];  // [B,S,D] f32
    const float* w_attn = (const float*)d_in[1];  // [D,3D]  f32
    const float* b_attn = (const float*)d_in[2];  // [3D]    f32
    const float* w_proj = (const float*)d_in[3];  // [D,D]   f32
    const float* b_proj = (const float*)d_in[4];  // [D]     f32

    char* ws = (char*)d_ws;
    unsigned short* wattn_t = (unsigned short*)ws;                 // [3072][1024] bf16
    unsigned short* wproj_t = (unsigned short*)(ws + 6291456);     // [1024][1024] bf16
    unsigned short* xb      = (unsigned short*)(ws + 8388608);     // [B*S][D] bf16
    unsigned short* qb      = (unsigned short*)(ws + 25165824);    // [B,H,S,DH] bf16
    unsigned short* kb      = (unsigned short*)(ws + 41943040);
    unsigned short* vtb     = (unsigned short*)(ws + 58720256);    // [B,H,DH,S] bf16
    unsigned short* aob     = (unsigned short*)(ws + 75497472);    // [B,S,D] bf16

    prep_fused<<<dim3(8192), 256, 0, stream>>>(x, w_attn, w_proj, xb, wattn_t, wproj_t);
    gemm_bt<<<dim3(24, 64), 256, 0, stream>>>(xb, wattn_t, b_attn, 0, qb, kb, vtb, nullptr);
    attn_fwd<<<dim3(512), 512, 0, stream>>>(qb, kb, vtb, aob);
    gemm_bt<<<dim3(8, 64), 256, 0, stream>>>(aob, wproj_t, b_proj, 1,
                                             nullptr, nullptr, nullptr, (float*)d_out);
}